// Round 6
// baseline (147.069 us; speedup 1.0000x reference)
//
#include <hip/hip_runtime.h>
#include <stdint.h>

#define H_  16
#define B_  4
#define S_  1024
#define D_  1024
#define HD  64
#define BQ  64
#define BK  64
#define NQT (S_/BQ)   // 16

typedef float          f32x4  __attribute__((ext_vector_type(4)));
typedef __bf16         bf16x8 __attribute__((ext_vector_type(8)));
typedef unsigned short us8    __attribute__((ext_vector_type(8)));
typedef unsigned short us4    __attribute__((ext_vector_type(4)));

union U8 { us8 u; bf16x8 b; };

__device__ __forceinline__ unsigned short f2bf(float f) {
    union { float f; uint32_t u; } a; a.f = f;
    uint32_t u = a.u;
    u += 0x7fffu + ((u >> 16) & 1u);   // RNE
    return (unsigned short)(u >> 16);
}
__device__ __forceinline__ float bf2f(unsigned short h) {
    union { uint32_t u; float f; } a; a.u = ((uint32_t)h) << 16;
    return a.f;
}

// Flash attention fwd, causal. 1 block = 4 waves = 64 q-rows of one (b,h).
// QK^T in bf16 hi/lo split (3 MFMA, ~fp32 accuracy), softmax fp32 (exp2 domain),
// PV in plain bf16. MFMA 16x16x32.
__global__ __launch_bounds__(256, 4)
void fa_fwd(const float* __restrict__ Qg, const float* __restrict__ Kg,
            const float* __restrict__ Vg, float* __restrict__ Og)
{
    __shared__ unsigned short Kh[BK][72];      // K hi, row-major [krow][d]
    __shared__ unsigned short Kl[BK][72];      // K lo
    __shared__ unsigned short Vt[HD][72];      // V transposed [d][krow]
    __shared__ unsigned short Pw[4][16][72];   // per-wave P transpose strip

    const int tid = threadIdx.x;
    const int w   = tid >> 6;     // wave 0..3
    const int l   = tid & 63;
    const int lg  = l >> 4;       // lane group 0..3
    const int li  = l & 15;

    const int qt = (NQT - 1) - (int)(blockIdx.x >> 6);  // heavy tiles first
    const int bh = blockIdx.x & 63;
    const int b  = bh >> 4;
    const int h  = bh & 15;

    const size_t base = ((size_t)b * S_) * D_ + (size_t)h * HD;

    // ---- Q fragments: scaled by hd^-0.5 * log2(e), split hi/lo bf16 ----
    bf16x8 qh[2], ql[2];
    {
        const float qs = 0.125f * 1.44269504088896340736f;
        const int qrow = qt*BQ + w*16 + li;
        #pragma unroll
        for (int ks = 0; ks < 2; ++ks) {
            const float4* p = (const float4*)(Qg + base + (size_t)qrow*D_ + ks*32 + lg*8);
            float4 x0 = p[0], x1 = p[1];
            float f[8] = {x0.x,x0.y,x0.z,x0.w,x1.x,x1.y,x1.z,x1.w};
            U8 uh, ul;
            #pragma unroll
            for (int j = 0; j < 8; ++j) {
                float v = f[j] * qs;
                unsigned short hh = f2bf(v);
                uh.u[j] = hh;
                ul.u[j] = f2bf(v - bf2f(hh));
            }
            qh[ks] = uh.b; ql[ks] = ul.b;
        }
    }

    f32x4 o[4] = {};          // o[d-tile][reg]
    float m_run[4], l_run[4];
    #pragma unroll
    for (int i = 0; i < 4; ++i) { m_run[i] = -1e30f; l_run[i] = 0.f; }

    for (int kt = 0; kt <= qt; ++kt) {
        __syncthreads();   // protect LDS K/V from previous iteration's readers

        // ---- stage K tile -> bf16 hi/lo in LDS (coalesced float4 loads) ----
        #pragma unroll
        for (int p = 0; p < 4; ++p) {
            const int row = p*16 + w*4 + lg;   // 0..63
            const float4* kp = (const float4*)(Kg + base + (size_t)(kt*BK + row)*D_ + li*4);
            float4 x = *kp;
            float f[4] = {x.x, x.y, x.z, x.w};
            us4 hh, ll;
            #pragma unroll
            for (int j = 0; j < 4; ++j) {
                unsigned short t = f2bf(f[j]);
                hh[j] = t;
                ll[j] = f2bf(f[j] - bf2f(t));
            }
            *(us4*)&Kh[row][li*4] = hh;
            *(us4*)&Kl[row][li*4] = ll;
        }

        // ---- stage V tile transposed: Vt[d][krow] (coalesced dword loads) ----
        {
            const float* vp = Vg + base + (size_t)(kt*BK + w*16)*D_ + l;
            unsigned short vv[16];
            #pragma unroll
            for (int r = 0; r < 16; ++r) vv[r] = f2bf(vp[(size_t)r*D_]);
            U8 a0, a1;
            #pragma unroll
            for (int j = 0; j < 8; ++j) { a0.u[j] = vv[j]; a1.u[j] = vv[8+j]; }
            *(us8*)&Vt[l][w*16]     = a0.u;
            *(us8*)&Vt[l][w*16 + 8] = a1.u;
        }

        __syncthreads();

        // ---- S = Q K^T  (split: QhKh + QlKh + QhKl) ----
        f32x4 s[4];
        #pragma unroll
        for (int nt = 0; nt < 4; ++nt) {
            f32x4 acc = {};
            #pragma unroll
            for (int ks = 0; ks < 2; ++ks) {
                const int krow = nt*16 + li;
                U8 kh, kl;
                kh.u = *(const us8*)&Kh[krow][ks*32 + lg*8];
                kl.u = *(const us8*)&Kl[krow][ks*32 + lg*8];
                acc = __builtin_amdgcn_mfma_f32_16x16x32_bf16(qh[ks], kh.b, acc, 0, 0, 0);
                acc = __builtin_amdgcn_mfma_f32_16x16x32_bf16(ql[ks], kh.b, acc, 0, 0, 0);
                acc = __builtin_amdgcn_mfma_f32_16x16x32_bf16(qh[ks], kl.b, acc, 0, 0, 0);
            }
            s[nt] = acc;
        }

        // ---- causal mask on diagonal tile ----
        if (kt == qt) {
            #pragma unroll
            for (int nt = 0; nt < 4; ++nt) {
                const int kcol = nt*16 + li;
                #pragma unroll
                for (int i = 0; i < 4; ++i) {
                    const int qrow = w*16 + lg*4 + i;
                    if (kcol > qrow) s[nt][i] = -1e30f;
                }
            }
        }

        // ---- online softmax (rows live in 16-lane groups; exp2 domain) ----
        #pragma unroll
        for (int i = 0; i < 4; ++i) {
            float pm = fmaxf(fmaxf(s[0][i], s[1][i]), fmaxf(s[2][i], s[3][i]));
            pm = fmaxf(pm, __shfl_xor(pm, 1));
            pm = fmaxf(pm, __shfl_xor(pm, 2));
            pm = fmaxf(pm, __shfl_xor(pm, 4));
            pm = fmaxf(pm, __shfl_xor(pm, 8));
            const float mn = fmaxf(m_run[i], pm);
            const float sc = exp2f(m_run[i] - mn);
            m_run[i] = mn;
            float rs = 0.f;
            #pragma unroll
            for (int nt = 0; nt < 4; ++nt) {
                float p = exp2f(s[nt][i] - mn);
                s[nt][i] = p;
                rs += p;
            }
            rs += __shfl_xor(rs, 1);
            rs += __shfl_xor(rs, 2);
            rs += __shfl_xor(rs, 4);
            rs += __shfl_xor(rs, 8);
            l_run[i] = l_run[i]*sc + rs;
            #pragma unroll
            for (int nt = 0; nt < 4; ++nt) o[nt][i] *= sc;
        }

        // ---- P -> bf16, transpose via per-wave LDS strip ----
        #pragma unroll
        for (int nt = 0; nt < 4; ++nt)
            #pragma unroll
            for (int i = 0; i < 4; ++i)
                Pw[w][lg*4 + i][nt*16 + li] = f2bf(s[nt][i]);

        // ---- O += P V ----
        #pragma unroll
        for (int ks = 0; ks < 2; ++ks) {
            U8 pa;
            pa.u = *(const us8*)&Pw[w][li][ks*32 + lg*8];
            #pragma unroll
            for (int nt = 0; nt < 4; ++nt) {
                U8 vb;
                vb.u = *(const us8*)&Vt[nt*16 + li][ks*32 + lg*8];
                o[nt] = __builtin_amdgcn_mfma_f32_16x16x32_bf16(pa.b, vb.b, o[nt], 0, 0, 0);
            }
        }
    }

    // ---- epilogue: normalize and store fp32 ----
    #pragma unroll
    for (int i = 0; i < 4; ++i) {
        const float inv = 1.0f / l_run[i];
        const int qrow = qt*BQ + w*16 + lg*4 + i;
        float* op = Og + base + (size_t)qrow*D_;
        #pragma unroll
        for (int nt = 0; nt < 4; ++nt)
            op[nt*16 + li] = o[nt][i] * inv;
    }
}

extern "C" void kernel_launch(void* const* d_in, const int* in_sizes, int n_in,
                              void* d_out, int out_size, void* d_ws, size_t ws_size,
                              hipStream_t stream) {
    const float* q = (const float*)d_in[0];
    const float* k = (const float*)d_in[1];
    const float* v = (const float*)d_in[2];
    float* out = (float*)d_out;
    dim3 grid(NQT * B_ * H_);   // 1024 blocks, heavy q-tiles first
    dim3 block(256);
    hipLaunchKernelGGL(fa_fwd, grid, block, 0, stream, q, k, v, out);
}

// Round 14
// 136.070 us; speedup vs baseline: 1.0808x; 1.0808x over previous
//
#include <hip/hip_runtime.h>
#include <stdint.h>

#define H_  16
#define B_  4
#define S_  1024
#define D_  1024
#define HD  64
#define BQ  64
#define BK  64
#define NQT (S_/BQ)   // 16

typedef float          f32x4  __attribute__((ext_vector_type(4)));
typedef __bf16         bf16x8 __attribute__((ext_vector_type(8)));
typedef unsigned short us8    __attribute__((ext_vector_type(8)));
typedef unsigned short us4    __attribute__((ext_vector_type(4)));

union U8 { us8 u; bf16x8 b; };

__device__ __forceinline__ unsigned short f2bf(float f) {
    union { float f; uint32_t u; } a; a.f = f;
    uint32_t u = a.u;
    u += 0x7fffu + ((u >> 16) & 1u);   // RNE
    return (unsigned short)(u >> 16);
}
__device__ __forceinline__ float bf2f(unsigned short h) {
    union { uint32_t u; float f; } a; a.u = ((uint32_t)h) << 16;
    return a.f;
}

// Flash attention fwd, causal. R7 structure + T5 setprio:
//  - balanced pairing: block handles q-tiles (15-p, p) => 17 iters/block, grid 512
//  - register-prefetch pipeline (T14): global K/V loads for tile kt+1 issued into
//    VGPRs during compute of tile kt; convert+LDS-write in the next write-phase.
//  - s_setprio(1) around MFMA clusters (T5): biases CU scheduler toward the
//    MFMA-issuing wave; helps when co-resident blocks are at different phases.
// QK^T in bf16 hi/lo split (3 MFMA), softmax fp32 exp2-domain, PV plain bf16.
__global__ __launch_bounds__(256, 2)
void fa_fwd(const float* __restrict__ Qg, const float* __restrict__ Kg,
            const float* __restrict__ Vg, float* __restrict__ Og)
{
    __shared__ unsigned short Kh[BK][72];      // K hi, row-major [krow][d]
    __shared__ unsigned short Kl[BK][72];      // K lo
    __shared__ unsigned short Vt[HD][72];      // V transposed [d][krow]
    __shared__ unsigned short Pw[4][16][72];   // per-wave P transpose strip

    const int tid = threadIdx.x;
    const int w   = tid >> 6;     // wave 0..3
    const int l   = tid & 63;
    const int lg  = l >> 4;       // lane group 0..3
    const int li  = l & 15;

    const int bh = blockIdx.x & 63;
    const int pr = blockIdx.x >> 6;      // pair index 0..7
    const int b  = bh >> 4;
    const int h  = bh & 15;

    const size_t base = ((size_t)b * S_) * D_ + (size_t)h * HD;

    const int qts[2] = { NQT - 1 - pr, pr };   // heavy tile first

    float4 kreg[4];      // prefetched K rows (fp32)
    float  vreg[16];     // prefetched V column slice (fp32)

    #pragma unroll 1
    for (int ti = 0; ti < 2; ++ti) {
        const int qt = qts[ti];

        // ---- Q fragments for this tile: scaled by hd^-0.5 * log2(e), hi/lo split ----
        bf16x8 qh[2], ql[2];
        {
            const float qs = 0.125f * 1.44269504088896340736f;
            const int qrow = qt*BQ + w*16 + li;
            #pragma unroll
            for (int ks = 0; ks < 2; ++ks) {
                const float4* p = (const float4*)(Qg + base + (size_t)qrow*D_ + ks*32 + lg*8);
                float4 x0 = p[0], x1 = p[1];
                float f[8] = {x0.x,x0.y,x0.z,x0.w,x1.x,x1.y,x1.z,x1.w};
                U8 uh, ul;
                #pragma unroll
                for (int j = 0; j < 8; ++j) {
                    float v = f[j] * qs;
                    unsigned short hh = f2bf(v);
                    uh.u[j] = hh;
                    ul.u[j] = f2bf(v - bf2f(hh));
                }
                qh[ks] = uh.b; ql[ks] = ul.b;
            }
        }

        f32x4 o[4] = {};          // o[d-tile][reg]
        float m_run[4], l_run[4];
        #pragma unroll
        for (int i = 0; i < 4; ++i) { m_run[i] = -1e30f; l_run[i] = 0.f; }

        // ---- prologue: load kt=0 K/V into registers ----
        #pragma unroll
        for (int pp = 0; pp < 4; ++pp)
            kreg[pp] = *(const float4*)(Kg + base + (size_t)(0*BK + pp*16 + w*4 + lg)*D_ + li*4);
        {
            const float* vp = Vg + base + (size_t)(0*BK + w*16)*D_ + l;
            #pragma unroll
            for (int r = 0; r < 16; ++r) vreg[r] = vp[(size_t)r*D_];
        }

        #pragma unroll 1
        for (int kt = 0; kt <= qt; ++kt) {
            __syncthreads();   // all waves done reading LDS from previous iter

            // ---- write-phase: convert prefetched regs -> LDS ----
            #pragma unroll
            for (int pp = 0; pp < 4; ++pp) {
                const int row = pp*16 + w*4 + lg;
                float f[4] = {kreg[pp].x, kreg[pp].y, kreg[pp].z, kreg[pp].w};
                us4 hh, ll;
                #pragma unroll
                for (int j = 0; j < 4; ++j) {
                    unsigned short t = f2bf(f[j]);
                    hh[j] = t;
                    ll[j] = f2bf(f[j] - bf2f(t));
                }
                *(us4*)&Kh[row][li*4] = hh;
                *(us4*)&Kl[row][li*4] = ll;
            }
            {
                U8 a0, a1;
                #pragma unroll
                for (int j = 0; j < 8; ++j) { a0.u[j] = f2bf(vreg[j]); a1.u[j] = f2bf(vreg[8+j]); }
                *(us8*)&Vt[l][w*16]     = a0.u;
                *(us8*)&Vt[l][w*16 + 8] = a1.u;
            }

            // ---- issue next tile's global loads (land during compute) ----
            if (kt < qt) {
                #pragma unroll
                for (int pp = 0; pp < 4; ++pp)
                    kreg[pp] = *(const float4*)(Kg + base + (size_t)((kt+1)*BK + pp*16 + w*4 + lg)*D_ + li*4);
                const float* vp = Vg + base + (size_t)((kt+1)*BK + w*16)*D_ + l;
                #pragma unroll
                for (int r = 0; r < 16; ++r) vreg[r] = vp[(size_t)r*D_];
            }

            __syncthreads();   // LDS tile ready

            // ---- S = Q K^T  (split: QhKh + QlKh + QhKl) ----
            f32x4 s[4];
            __builtin_amdgcn_s_setprio(1);
            #pragma unroll
            for (int nt = 0; nt < 4; ++nt) {
                f32x4 acc = {};
                #pragma unroll
                for (int ks = 0; ks < 2; ++ks) {
                    const int krow = nt*16 + li;
                    U8 kh, kl;
                    kh.u = *(const us8*)&Kh[krow][ks*32 + lg*8];
                    kl.u = *(const us8*)&Kl[krow][ks*32 + lg*8];
                    acc = __builtin_amdgcn_mfma_f32_16x16x32_bf16(qh[ks], kh.b, acc, 0, 0, 0);
                    acc = __builtin_amdgcn_mfma_f32_16x16x32_bf16(ql[ks], kh.b, acc, 0, 0, 0);
                    acc = __builtin_amdgcn_mfma_f32_16x16x32_bf16(qh[ks], kl.b, acc, 0, 0, 0);
                }
                s[nt] = acc;
            }
            __builtin_amdgcn_s_setprio(0);

            // ---- causal mask on diagonal tile ----
            if (kt == qt) {
                #pragma unroll
                for (int nt = 0; nt < 4; ++nt) {
                    const int kcol = nt*16 + li;
                    #pragma unroll
                    for (int i = 0; i < 4; ++i) {
                        const int qrow = w*16 + lg*4 + i;
                        if (kcol > qrow) s[nt][i] = -1e30f;
                    }
                }
            }

            // ---- online softmax (rows live in 16-lane groups; exp2 domain) ----
            #pragma unroll
            for (int i = 0; i < 4; ++i) {
                float pm = fmaxf(fmaxf(s[0][i], s[1][i]), fmaxf(s[2][i], s[3][i]));
                pm = fmaxf(pm, __shfl_xor(pm, 1));
                pm = fmaxf(pm, __shfl_xor(pm, 2));
                pm = fmaxf(pm, __shfl_xor(pm, 4));
                pm = fmaxf(pm, __shfl_xor(pm, 8));
                const float mn = fmaxf(m_run[i], pm);
                const float sc = exp2f(m_run[i] - mn);
                m_run[i] = mn;
                float rs = 0.f;
                #pragma unroll
                for (int nt = 0; nt < 4; ++nt) {
                    float p = exp2f(s[nt][i] - mn);
                    s[nt][i] = p;
                    rs += p;
                }
                rs += __shfl_xor(rs, 1);
                rs += __shfl_xor(rs, 2);
                rs += __shfl_xor(rs, 4);
                rs += __shfl_xor(rs, 8);
                l_run[i] = l_run[i]*sc + rs;
                #pragma unroll
                for (int nt = 0; nt < 4; ++nt) o[nt][i] *= sc;
            }

            // ---- P -> bf16, transpose via per-wave LDS strip ----
            #pragma unroll
            for (int nt = 0; nt < 4; ++nt)
                #pragma unroll
                for (int i = 0; i < 4; ++i)
                    Pw[w][lg*4 + i][nt*16 + li] = f2bf(s[nt][i]);

            // ---- O += P V ----
            __builtin_amdgcn_s_setprio(1);
            #pragma unroll
            for (int ks = 0; ks < 2; ++ks) {
                U8 pa;
                pa.u = *(const us8*)&Pw[w][li][ks*32 + lg*8];
                #pragma unroll
                for (int nt = 0; nt < 4; ++nt) {
                    U8 vb;
                    vb.u = *(const us8*)&Vt[nt*16 + li][ks*32 + lg*8];
                    o[nt] = __builtin_amdgcn_mfma_f32_16x16x32_bf16(pa.b, vb.b, o[nt], 0, 0, 0);
                }
            }
            __builtin_amdgcn_s_setprio(0);
        }

        // ---- epilogue: normalize and store fp32 ----
        #pragma unroll
        for (int i = 0; i < 4; ++i) {
            const float inv = 1.0f / l_run[i];
            const int qrow = qt*BQ + w*16 + lg*4 + i;
            float* op = Og + base + (size_t)qrow*D_;
            #pragma unroll
            for (int nt = 0; nt < 4; ++nt)
                op[nt*16 + li] = o[nt][i] * inv;
        }
    }
}

extern "C" void kernel_launch(void* const* d_in, const int* in_sizes, int n_in,
                              void* d_out, int out_size, void* d_ws, size_t ws_size,
                              hipStream_t stream) {
    const float* q = (const float*)d_in[0];
    const float* k = (const float*)d_in[1];
    const float* v = (const float*)d_in[2];
    float* out = (float*)d_out;
    dim3 grid(8 * B_ * H_);   // 512 blocks: 64 (b,h) x 8 balanced q-tile pairs
    dim3 block(256);
    hipLaunchKernelGGL(fa_fwd, grid, block, 0, stream, q, k, v, out);
}

// Round 15
// 129.517 us; speedup vs baseline: 1.1355x; 1.0506x over previous
//
#include <hip/hip_runtime.h>
#include <stdint.h>

#define H_  16
#define B_  4
#define S_  1024
#define D_  1024
#define HD  64
#define BQ  64
#define BK  64
#define NQT (S_/BQ)   // 16

typedef float          f32x4  __attribute__((ext_vector_type(4)));
typedef __bf16         bf16x8 __attribute__((ext_vector_type(8)));
typedef unsigned short us8    __attribute__((ext_vector_type(8)));
typedef unsigned short us4    __attribute__((ext_vector_type(4)));

union U8 { us8 u; bf16x8 b; };
union BU { __bf16 b; unsigned short u; };

__device__ __forceinline__ unsigned short f2bf16(float f) {
    BU c; c.b = (__bf16)f; return c.u;   // native cvt (RNE), compiler packs pairs
}

// Flash attention fwd, causal. R14 structure:
//  - balanced pairing: block handles q-tiles (15-p, p) => 17 iters/block, grid 512
//  - double-buffered K/V LDS: ONE barrier per iter; convert+write of tile kt+1
//    overlaps compute of tile kt (independent buffers, compiler interleaves)
//  - register-prefetch 2 tiles ahead (T14), native (__bf16) casts, T5 setprio
// QK^T in bf16 hi/lo split (3 MFMA, hi=native-rounded, lo=exact residual),
// softmax fp32 exp2-domain, PV plain bf16. MFMA 16x16x32.
__global__ __launch_bounds__(256, 2)
void fa_fwd(const float* __restrict__ Qg, const float* __restrict__ Kg,
            const float* __restrict__ Vg, float* __restrict__ Og)
{
    __shared__ unsigned short Kh[2][BK][72];   // K hi, [buf][krow][d]
    __shared__ unsigned short Kl[2][BK][72];   // K lo
    __shared__ unsigned short Vt[2][HD][72];   // V transposed [buf][d][krow]
    __shared__ unsigned short Pw[4][16][72];   // per-wave P transpose strip

    const int tid = threadIdx.x;
    const int w   = tid >> 6;     // wave 0..3
    const int l   = tid & 63;
    const int lg  = l >> 4;       // lane group 0..3
    const int li  = l & 15;

    const int bh = blockIdx.x & 63;
    const int pr = blockIdx.x >> 6;      // pair index 0..7
    const int b  = bh >> 4;
    const int h  = bh & 15;

    const size_t base = ((size_t)b * S_) * D_ + (size_t)h * HD;

    const int qts[2] = { NQT - 1 - pr, pr };   // heavy tile first

    float4 kreg[4];      // prefetched K rows (fp32)
    float  vreg[16];     // prefetched V column slice (fp32)

    // stage prefetched regs -> LDS buffer `buf` (convert fp32 -> bf16 hi/lo)
    auto stage = [&](int buf) {
        #pragma unroll
        for (int pp = 0; pp < 4; ++pp) {
            const int row = pp*16 + w*4 + lg;
            float fv[4] = {kreg[pp].x, kreg[pp].y, kreg[pp].z, kreg[pp].w};
            us4 hh, ll;
            #pragma unroll
            for (int j = 0; j < 4; ++j) {
                __bf16 hb = (__bf16)fv[j];
                BU c; c.b = hb; hh[j] = c.u;
                ll[j] = f2bf16(fv[j] - (float)hb);
            }
            *(us4*)&Kh[buf][row][li*4] = hh;
            *(us4*)&Kl[buf][row][li*4] = ll;
        }
        U8 a0, a1;
        #pragma unroll
        for (int j = 0; j < 8; ++j) { a0.u[j] = f2bf16(vreg[j]); a1.u[j] = f2bf16(vreg[8+j]); }
        *(us8*)&Vt[buf][l][w*16]     = a0.u;
        *(us8*)&Vt[buf][l][w*16 + 8] = a1.u;
    };
    // issue global loads of K/V tile `kt2` into regs
    auto loadkv = [&](int kt2) {
        #pragma unroll
        for (int pp = 0; pp < 4; ++pp)
            kreg[pp] = *(const float4*)(Kg + base + (size_t)(kt2*BK + pp*16 + w*4 + lg)*D_ + li*4);
        const float* vp = Vg + base + (size_t)(kt2*BK + w*16)*D_ + l;
        #pragma unroll
        for (int r = 0; r < 16; ++r) vreg[r] = vp[(size_t)r*D_];
    };

    #pragma unroll 1
    for (int ti = 0; ti < 2; ++ti) {
        const int qt = qts[ti];

        // ---- Q fragments: scaled by hd^-0.5 * log2(e), hi/lo split ----
        bf16x8 qh[2], ql[2];
        {
            const float qs = 0.125f * 1.44269504088896340736f;
            const int qrow = qt*BQ + w*16 + li;
            #pragma unroll
            for (int ks = 0; ks < 2; ++ks) {
                const float4* p = (const float4*)(Qg + base + (size_t)qrow*D_ + ks*32 + lg*8);
                float4 x0 = p[0], x1 = p[1];
                float f[8] = {x0.x,x0.y,x0.z,x0.w,x1.x,x1.y,x1.z,x1.w};
                U8 uh, ul;
                #pragma unroll
                for (int j = 0; j < 8; ++j) {
                    float v = f[j] * qs;
                    __bf16 hb = (__bf16)v;
                    BU c; c.b = hb; uh.u[j] = c.u;
                    ul.u[j] = f2bf16(v - (float)hb);
                }
                qh[ks] = uh.b; ql[ks] = ul.b;
            }
        }

        f32x4 o[4] = {};          // o[d-tile][reg]
        float m_run[4], l_run[4];
        #pragma unroll
        for (int i = 0; i < 4; ++i) { m_run[i] = -1e30f; l_run[i] = 0.f; }

        // ---- prologue: stage kt=0, prefetch kt=1 ----
        loadkv(0);
        stage(0);
        if (qt >= 1) loadkv(1);
        __syncthreads();

        #pragma unroll 1
        for (int kt = 0; kt <= qt; ++kt) {
            const int cur = kt & 1;

            // ---- S = Q K^T from buf cur (split: QhKh + QlKh + QhKl) ----
            f32x4 s[4];
            __builtin_amdgcn_s_setprio(1);
            #pragma unroll
            for (int nt = 0; nt < 4; ++nt) {
                f32x4 acc = {};
                #pragma unroll
                for (int ks = 0; ks < 2; ++ks) {
                    const int krow = nt*16 + li;
                    U8 kh, kl;
                    kh.u = *(const us8*)&Kh[cur][krow][ks*32 + lg*8];
                    kl.u = *(const us8*)&Kl[cur][krow][ks*32 + lg*8];
                    acc = __builtin_amdgcn_mfma_f32_16x16x32_bf16(qh[ks], kh.b, acc, 0, 0, 0);
                    acc = __builtin_amdgcn_mfma_f32_16x16x32_bf16(ql[ks], kh.b, acc, 0, 0, 0);
                    acc = __builtin_amdgcn_mfma_f32_16x16x32_bf16(qh[ks], kl.b, acc, 0, 0, 0);
                }
                s[nt] = acc;
            }
            __builtin_amdgcn_s_setprio(0);

            // ---- causal mask on diagonal tile ----
            if (kt == qt) {
                #pragma unroll
                for (int nt = 0; nt < 4; ++nt) {
                    const int kcol = nt*16 + li;
                    #pragma unroll
                    for (int i = 0; i < 4; ++i) {
                        const int qrow = w*16 + lg*4 + i;
                        if (kcol > qrow) s[nt][i] = -1e30f;
                    }
                }
            }

            // ---- online softmax (rows in 16-lane groups; exp2 domain) ----
            #pragma unroll
            for (int i = 0; i < 4; ++i) {
                float pm = fmaxf(fmaxf(s[0][i], s[1][i]), fmaxf(s[2][i], s[3][i]));
                pm = fmaxf(pm, __shfl_xor(pm, 1));
                pm = fmaxf(pm, __shfl_xor(pm, 2));
                pm = fmaxf(pm, __shfl_xor(pm, 4));
                pm = fmaxf(pm, __shfl_xor(pm, 8));
                const float mn = fmaxf(m_run[i], pm);
                const float sc = exp2f(m_run[i] - mn);
                m_run[i] = mn;
                float rs = 0.f;
                #pragma unroll
                for (int nt = 0; nt < 4; ++nt) {
                    float p = exp2f(s[nt][i] - mn);
                    s[nt][i] = p;
                    rs += p;
                }
                rs += __shfl_xor(rs, 1);
                rs += __shfl_xor(rs, 2);
                rs += __shfl_xor(rs, 4);
                rs += __shfl_xor(rs, 8);
                l_run[i] = l_run[i]*sc + rs;
                #pragma unroll
                for (int nt = 0; nt < 4; ++nt) o[nt][i] *= sc;
            }

            // ---- P -> bf16, transpose via per-wave LDS strip ----
            #pragma unroll
            for (int nt = 0; nt < 4; ++nt)
                #pragma unroll
                for (int i = 0; i < 4; ++i)
                    Pw[w][lg*4 + i][nt*16 + li] = f2bf16(s[nt][i]);

            // ---- O += P V (from buf cur) ----
            __builtin_amdgcn_s_setprio(1);
            #pragma unroll
            for (int ks = 0; ks < 2; ++ks) {
                U8 pa;
                pa.u = *(const us8*)&Pw[w][li][ks*32 + lg*8];
                #pragma unroll
                for (int nt = 0; nt < 4; ++nt) {
                    U8 vb;
                    vb.u = *(const us8*)&Vt[cur][nt*16 + li][ks*32 + lg*8];
                    o[nt] = __builtin_amdgcn_mfma_f32_16x16x32_bf16(pa.b, vb.b, o[nt], 0, 0, 0);
                }
            }
            __builtin_amdgcn_s_setprio(0);

            // ---- staging of tile kt+1 into buf cur^1 (overlaps compute) ----
            if (kt < qt) {
                stage(cur ^ 1);
                if (kt + 2 <= qt) loadkv(kt + 2);
            }
            __syncthreads();   // separates read(buf)@kt from write(buf)@kt+1
        }

        // ---- epilogue: normalize and store fp32 ----
        #pragma unroll
        for (int i = 0; i < 4; ++i) {
            const float inv = 1.0f / l_run[i];
            const int qrow = qt*BQ + w*16 + lg*4 + i;
            float* op = Og + base + (size_t)qrow*D_;
            #pragma unroll
            for (int nt = 0; nt < 4; ++nt)
                op[nt*16 + li] = o[nt][i] * inv;
        }
    }
}

extern "C" void kernel_launch(void* const* d_in, const int* in_sizes, int n_in,
                              void* d_out, int out_size, void* d_ws, size_t ws_size,
                              hipStream_t stream) {
    const float* q = (const float*)d_in[0];
    const float* k = (const float*)d_in[1];
    const float* v = (const float*)d_in[2];
    float* out = (float*)d_out;
    dim3 grid(8 * B_ * H_);   // 512 blocks: 64 (b,h) x 8 balanced q-tile pairs
    dim3 block(256);
    hipLaunchKernelGGL(fa_fwd, grid, block, 0, stream, q, k, v, out);
}